// Round 3
// baseline (765.193 us; speedup 1.0000x reference)
//
#include <hip/hip_runtime.h>
#include <hip/hip_bf16.h>
#include <stdint.h>

#define B_   64
#define N_   128
#define H_   256
#define FH   1024   // 4*H
#define NT   32     // trunks
#define TL   32     // trunk len
#define LV   3
#define OUT_ 10

typedef __attribute__((ext_vector_type(8))) short short8;
typedef __attribute__((ext_vector_type(4))) float f32x4;
typedef unsigned long long ull;

__device__ inline float sigmoidf_(float x) { return 1.0f / (1.0f + __expf(-x)); }
__device__ inline float tanhf_(float x) { float t = __expf(2.0f * x); return 1.0f - 2.0f / (t + 1.0f); }
__device__ inline unsigned short f2bf(float x) {
    union { float f; unsigned u; } v; v.f = x;
    unsigned r = (v.u + 0x7FFFu + ((v.u >> 16) & 1u)) >> 16;
    return (unsigned short)r;
}
__device__ inline float bf2f(unsigned short b) {
    union { unsigned u; float f; } v; v.u = ((unsigned)b) << 16; return v.f;
}

// prep 1: u[l][j] = W_ih[l][j,:] . W_enc ;  v[l][j] = W_ih[l][j,:] . b_enc + b_ih + b_hh
__global__ void prep_uv(const float* __restrict__ W_enc, const float* __restrict__ b_enc,
                        const float* __restrict__ W_ih, const float* __restrict__ b_ih,
                        const float* __restrict__ b_hh,
                        float* __restrict__ u, float* __restrict__ v) {
    int j = blockIdx.x;            // 0..3071  (l*1024 + jj)
    int lane = threadIdx.x;        // 0..63
    const float4 w  = ((const float4*)(W_ih + (size_t)j * H_))[lane];
    const float4 we = ((const float4*)W_enc)[lane];
    const float4 be = ((const float4*)b_enc)[lane];
    float du = w.x * we.x + w.y * we.y + w.z * we.z + w.w * we.w;
    float dv = w.x * be.x + w.y * be.y + w.z * be.z + w.w * be.w;
    for (int m = 32; m >= 1; m >>= 1) { du += __shfl_xor(du, m); dv += __shfl_xor(dv, m); }
    if (lane == 0) { u[j] = du; v[j] = dv + b_ih[j] + b_hh[j]; }
}

// prep 2: W_hh -> bf16 ; init out with sum_l b_lin ; zero the exchange flags
__global__ void prep_whh(const float* __restrict__ W_hh, unsigned short* __restrict__ whh_bf,
                         const float* __restrict__ b_lin, float* __restrict__ out,
                         int* __restrict__ flags) {
    int gid = blockIdx.x * blockDim.x + threadIdx.x;    // 0..196607, each converts 4
    const float4 w = ((const float4*)W_hh)[gid];
    ushort4 o;
    o.x = f2bf(w.x); o.y = f2bf(w.y); o.z = f2bf(w.z); o.w = f2bf(w.w);
    ((ushort4*)whh_bf)[gid] = o;
    if (gid < B_ * OUT_) {
        int oo = gid % OUT_;
        out[gid] = b_lin[oo] + b_lin[OUT_ + oo] + b_lin[2 * OUT_ + oo];
    }
    if (gid < 192) flags[gid] = 0;
}

// Main: 192 blocks = 96 trunk-pairs x 2 column-halves. W_hh slice in registers.
// Per-step cross-block h exchange: single-thread relaxed spin + early register
// publish + parity double-buffered hx. Own-half K MFMA runs before the wait.
__global__ __launch_bounds__(256, 1)
void lstm_main(const float* __restrict__ bfeat, const int* __restrict__ trunk_idx,
               const int* __restrict__ trunk_len,
               const unsigned short* __restrict__ whh_bf,
               const float* __restrict__ u, const float* __restrict__ v,
               const float* __restrict__ W_lin,
               unsigned short* __restrict__ hx, int* __restrict__ flags,
               float* __restrict__ out) {
    __shared__ __align__(16) unsigned short hbuf[64][264];   // full h, bf16, +8 pad
    __shared__ __align__(16) float svals[64];

    const int bid = blockIdx.x;
    const int q16 = bid & 15;
    const int cb  = q16 >> 3;            // column half
    const int pair = (bid >> 4) * 8 + (q16 & 7);   // partner bid^8 -> same XCD
    const int pbid = bid ^ 8;
    const int l = pair >> 5;
    const int t = pair & 31;

    const int tid = threadIdx.x;
    const int w = tid >> 6;
    const int lane = tid & 63;
    const int col = lane & 15;
    const int q = lane >> 4;

    const unsigned short* whh_l = whh_bf + (size_t)l * FH * H_;

    // W_hh slice -> registers. Wave w owns gate cols j = g*256 + cb*128 + w*32 + n*16 + col.
    // Breg[g*2+n][ks] covers K chunk [ks*32, ks*32+32) (global h index).
    short8 Breg[8][8];
    #pragma unroll
    for (int g = 0; g < 4; ++g)
        #pragma unroll
        for (int n = 0; n < 2; ++n) {
            int j = g * 256 + cb * 128 + w * 32 + n * 16 + col;
            const unsigned short* bp = whh_l + (size_t)j * H_ + q * 8;
            #pragma unroll
            for (int ks = 0; ks < 8; ++ks)
                Breg[g * 2 + n][ks] = *(const short8*)(bp + ks * 32);
        }

    float u_r[4][2], v_r[4][2];
    {
        const float* u_l = u + l * FH;
        const float* v_l = v + l * FH;
        #pragma unroll
        for (int g = 0; g < 4; ++g)
            #pragma unroll
            for (int n = 0; n < 2; ++n) {
                int j = g * 256 + cb * 128 + w * 32 + n * 16 + col;
                u_r[g][n] = u_l[j];
                v_r[g][n] = v_l[j];
            }
    }

    f32x4 c_r[4][2];
    #pragma unroll
    for (int mt = 0; mt < 4; ++mt)
        #pragma unroll
        for (int n = 0; n < 2; ++n)
            #pragma unroll
            for (int rg = 0; rg < 4; ++rg) c_r[mt][n][rg] = 0.0f;

    int len = trunk_len[l * NT + t];
    if (len < 1) len = 1;
    const int* tix = trunk_idx + (l * NT + t) * TL;

    unsigned short* hx_own = hx + (size_t)bid * 16384;        // 2 parity buffers x 8192
    const unsigned short* hx_par = hx + (size_t)pbid * 16384;
    const int prow = tid >> 2;
    const int pcol = (tid & 3) * 32;

    ushort4 hb16[4][2];   // new h (bf16) kept until end-of-step hbuf write

    for (int p = 0; p < len; ++p) {
        if (tid < 64) svals[tid] = bfeat[tid * N_ + tix[p]];
        __syncthreads();   // B1: svals ready; prev-step hbuf writes ready; partner slot free

        f32x4 sv[4];
        #pragma unroll
        for (int mt = 0; mt < 4; ++mt) sv[mt] = *(const f32x4*)&svals[mt * 16 + q * 4];

        const bool more = (p + 1 < len);
        unsigned short* pub = hx_own + ((p + 1) & 1) * 8192;

        // ================= pass n = 0 =================
        {
            f32x4 acc[4][4];   // [mt][g]
            #pragma unroll
            for (int mt = 0; mt < 4; ++mt)
                #pragma unroll
                for (int g = 0; g < 4; ++g)
                    #pragma unroll
                    for (int rg = 0; rg < 4; ++rg)
                        acc[mt][g][rg] = sv[mt][rg] * u_r[g][0] + v_r[g][0];

            if (p > 0) {
                // own-half K (no partner data needed) — hides the wait
                #pragma unroll
                for (int mt = 0; mt < 4; ++mt) {
                    short8 a_f[4];
                    #pragma unroll
                    for (int kk = 0; kk < 4; ++kk)
                        a_f[kk] = *(const short8*)&hbuf[mt * 16 + col][cb * 128 + kk * 32 + q * 8];
                    #pragma unroll
                    for (int g = 0; g < 4; ++g)
                        #pragma unroll
                        for (int kk = 0; kk < 4; ++kk)
                            acc[mt][g] = __builtin_amdgcn_mfma_f32_16x16x32_bf16(
                                a_f[kk], Breg[g * 2][cb * 4 + kk], acc[mt][g], 0, 0, 0);
                }
                // wait for partner's h^(p): ONE thread, relaxed spin
                if (tid == 0) {
                    while (__hip_atomic_load(&flags[pbid], __ATOMIC_RELAXED,
                                             __HIP_MEMORY_SCOPE_AGENT) < p)
                        __builtin_amdgcn_s_sleep(2);
                }
                __syncthreads();   // B2: flag observed
                __builtin_amdgcn_fence(__ATOMIC_ACQUIRE, "agent");
                // pull partner half (row-major, 64 B/thread) into LDS
                {
                    const ull* src = (const ull*)(hx_par + (size_t)((p & 1) * 8192) + prow * 128 + pcol);
                    ull* dst = (ull*)&hbuf[prow][(1 - cb) * 128 + pcol];
                    #pragma unroll
                    for (int i = 0; i < 8; ++i)
                        dst[i] = __hip_atomic_load(&src[i], __ATOMIC_RELAXED, __HIP_MEMORY_SCOPE_AGENT);
                }
                __syncthreads();   // B3: partner half in LDS
                #pragma unroll
                for (int mt = 0; mt < 4; ++mt) {
                    short8 a_f[4];
                    #pragma unroll
                    for (int kk = 0; kk < 4; ++kk)
                        a_f[kk] = *(const short8*)&hbuf[mt * 16 + col][(1 - cb) * 128 + kk * 32 + q * 8];
                    #pragma unroll
                    for (int g = 0; g < 4; ++g)
                        #pragma unroll
                        for (int kk = 0; kk < 4; ++kk)
                            acc[mt][g] = __builtin_amdgcn_mfma_f32_16x16x32_bf16(
                                a_f[kk], Breg[g * 2][(1 - cb) * 4 + kk], acc[mt][g], 0, 0, 0);
                }
            }

            // nonlinearities; publish n=0 slice immediately from registers
            #pragma unroll
            for (int mt = 0; mt < 4; ++mt) {
                ushort4 hb;
                #pragma unroll
                for (int rg = 0; rg < 4; ++rg) {
                    float si = sigmoidf_(acc[mt][0][rg]);
                    float sf = sigmoidf_(acc[mt][1][rg]);
                    float tg = tanhf_(acc[mt][2][rg]);
                    float so = sigmoidf_(acc[mt][3][rg]);
                    float cn = sf * c_r[mt][0][rg] + si * tg;
                    c_r[mt][0][rg] = cn;
                    unsigned short hv = f2bf(so * tanhf_(cn));
                    ((unsigned short*)&hb)[rg] = hv;
                    if (more) {
                        int row = mt * 16 + q * 4 + rg;
                        __hip_atomic_store(&pub[row * 128 + w * 32 + col], hv,
                                           __ATOMIC_RELAXED, __HIP_MEMORY_SCOPE_AGENT);
                    }
                }
                hb16[mt][0] = hb;
            }
        }

        // ================= pass n = 1 =================
        {
            f32x4 acc[4][4];
            #pragma unroll
            for (int mt = 0; mt < 4; ++mt)
                #pragma unroll
                for (int g = 0; g < 4; ++g)
                    #pragma unroll
                    for (int rg = 0; rg < 4; ++rg)
                        acc[mt][g][rg] = sv[mt][rg] * u_r[g][1] + v_r[g][1];

            if (p > 0) {
                #pragma unroll
                for (int mt = 0; mt < 4; ++mt) {
                    short8 a_f[4];
                    #pragma unroll
                    for (int kk = 0; kk < 4; ++kk)
                        a_f[kk] = *(const short8*)&hbuf[mt * 16 + col][cb * 128 + kk * 32 + q * 8];
                    #pragma unroll
                    for (int g = 0; g < 4; ++g)
                        #pragma unroll
                        for (int kk = 0; kk < 4; ++kk)
                            acc[mt][g] = __builtin_amdgcn_mfma_f32_16x16x32_bf16(
                                a_f[kk], Breg[g * 2 + 1][cb * 4 + kk], acc[mt][g], 0, 0, 0);
                }
                #pragma unroll
                for (int mt = 0; mt < 4; ++mt) {
                    short8 a_f[4];
                    #pragma unroll
                    for (int kk = 0; kk < 4; ++kk)
                        a_f[kk] = *(const short8*)&hbuf[mt * 16 + col][(1 - cb) * 128 + kk * 32 + q * 8];
                    #pragma unroll
                    for (int g = 0; g < 4; ++g)
                        #pragma unroll
                        for (int kk = 0; kk < 4; ++kk)
                            acc[mt][g] = __builtin_amdgcn_mfma_f32_16x16x32_bf16(
                                a_f[kk], Breg[g * 2 + 1][(1 - cb) * 4 + kk], acc[mt][g], 0, 0, 0);
                }
            }

            #pragma unroll
            for (int mt = 0; mt < 4; ++mt) {
                ushort4 hb;
                #pragma unroll
                for (int rg = 0; rg < 4; ++rg) {
                    float si = sigmoidf_(acc[mt][0][rg]);
                    float sf = sigmoidf_(acc[mt][1][rg]);
                    float tg = tanhf_(acc[mt][2][rg]);
                    float so = sigmoidf_(acc[mt][3][rg]);
                    float cn = sf * c_r[mt][1][rg] + si * tg;
                    c_r[mt][1][rg] = cn;
                    unsigned short hv = f2bf(so * tanhf_(cn));
                    ((unsigned short*)&hb)[rg] = hv;
                    if (more) {
                        int row = mt * 16 + q * 4 + rg;
                        __hip_atomic_store(&pub[row * 128 + w * 32 + 16 + col], hv,
                                           __ATOMIC_RELAXED, __HIP_MEMORY_SCOPE_AGENT);
                    }
                }
                hb16[mt][1] = hb;
            }
        }

        if (more) __builtin_amdgcn_fence(__ATOMIC_RELEASE, "agent");
        __syncthreads();   // B4: all hbuf reads done; publish stores drained (barrier waits vmcnt 0)
        if (more && tid == 0)
            __hip_atomic_store(&flags[bid], p + 1, __ATOMIC_RELEASE, __HIP_MEMORY_SCOPE_AGENT);

        // write new own-half h into hbuf (next step / epilogue reads after B1)
        #pragma unroll
        for (int mt = 0; mt < 4; ++mt)
            #pragma unroll
            for (int n = 0; n < 2; ++n)
                #pragma unroll
                for (int rg = 0; rg < 4; ++rg)
                    hbuf[mt * 16 + q * 4 + rg][cb * 128 + w * 32 + n * 16 + col] =
                        ((unsigned short*)&hb16[mt][n])[rg];
    }

    __syncthreads();
    // epilogue: project own half of h_last to OUT, accumulate
    const float* wl = W_lin + l * H_ * OUT_;
    for (int task = tid; task < B_ * OUT_; task += 256) {
        int m = task / OUT_, o = task % OUT_;
        float s = 0.f;
        for (int k = 0; k < 128; ++k)
            s += bf2f(hbuf[m][cb * 128 + k]) * wl[(cb * 128 + k) * OUT_ + o];
        atomicAdd(&out[m * OUT_ + o], s);
    }
}

extern "C" void kernel_launch(void* const* d_in, const int* in_sizes, int n_in,
                              void* d_out, int out_size, void* d_ws, size_t ws_size,
                              hipStream_t stream) {
    const float* bfeat = (const float*)d_in[0];
    const int*   tidx  = (const int*)d_in[1];
    const int*   tlen  = (const int*)d_in[2];
    const float* W_enc = (const float*)d_in[3];
    const float* b_enc = (const float*)d_in[4];
    const float* W_ih  = (const float*)d_in[5];
    const float* W_hh  = (const float*)d_in[6];
    const float* b_ih  = (const float*)d_in[7];
    const float* b_hh  = (const float*)d_in[8];
    const float* W_lin = (const float*)d_in[9];
    const float* b_lin = (const float*)d_in[10];
    float* out = (float*)d_out;

    // ws layout
    unsigned short* whh_bf = (unsigned short*)d_ws;                       // 1,572,864 B
    float* u = (float*)((char*)d_ws + 1572864);                           // 12,288 B
    float* v = (float*)((char*)d_ws + 1572864 + 12288);                   // 12,288 B
    unsigned short* hx = (unsigned short*)((char*)d_ws + 1597440);        // 6,291,456 B (2-parity)
    int* flags = (int*)((char*)d_ws + 1597440 + 6291456);                 // 768 B

    prep_uv<<<LV * FH, 64, 0, stream>>>(W_enc, b_enc, W_ih, b_ih, b_hh, u, v);
    prep_whh<<<768, 256, 0, stream>>>(W_hh, whh_bf, b_lin, out, flags);
    lstm_main<<<192, 256, 0, stream>>>(bfeat, tidx, tlen, whh_bf, u, v, W_lin, hx, flags, out);
}

// Round 4
// 737.717 us; speedup vs baseline: 1.0372x; 1.0372x over previous
//
#include <hip/hip_runtime.h>
#include <hip/hip_bf16.h>
#include <stdint.h>

#define B_   64
#define N_   128
#define H_   256
#define FH   1024   // 4*H
#define NT   32     // trunks
#define TL   32     // trunk len
#define LV   3
#define OUT_ 10
#define FLAG_STRIDE 64   // ints: one flag per 256 B line (kill false sharing)

typedef __attribute__((ext_vector_type(8))) short short8;
typedef __attribute__((ext_vector_type(4))) float f32x4;
typedef unsigned long long ull;

__device__ inline float sigmoidf_(float x) { return 1.0f / (1.0f + __expf(-x)); }
__device__ inline float tanhf_(float x) { float t = __expf(2.0f * x); return 1.0f - 2.0f / (t + 1.0f); }
__device__ inline unsigned short f2bf(float x) {
    union { float f; unsigned u; } v; v.f = x;
    unsigned r = (v.u + 0x7FFFu + ((v.u >> 16) & 1u)) >> 16;
    return (unsigned short)r;
}
__device__ inline float bf2f(unsigned short b) {
    union { unsigned u; float f; } v; v.u = ((unsigned)b) << 16; return v.f;
}

// prep 1: u[l][j] = W_ih[l][j,:] . W_enc ;  v[l][j] = W_ih[l][j,:] . b_enc + b_ih + b_hh
__global__ void prep_uv(const float* __restrict__ W_enc, const float* __restrict__ b_enc,
                        const float* __restrict__ W_ih, const float* __restrict__ b_ih,
                        const float* __restrict__ b_hh,
                        float* __restrict__ u, float* __restrict__ v) {
    int j = blockIdx.x;            // 0..3071
    int lane = threadIdx.x;        // 0..63
    const float4 w  = ((const float4*)(W_ih + (size_t)j * H_))[lane];
    const float4 we = ((const float4*)W_enc)[lane];
    const float4 be = ((const float4*)b_enc)[lane];
    float du = w.x * we.x + w.y * we.y + w.z * we.z + w.w * we.w;
    float dv = w.x * be.x + w.y * be.y + w.z * be.z + w.w * be.w;
    for (int m = 32; m >= 1; m >>= 1) { du += __shfl_xor(du, m); dv += __shfl_xor(dv, m); }
    if (lane == 0) { u[j] = du; v[j] = dv + b_ih[j] + b_hh[j]; }
}

// prep 2: W_hh -> bf16 ; init out with sum_l b_lin ; zero the (padded) exchange flags
__global__ void prep_whh(const float* __restrict__ W_hh, unsigned short* __restrict__ whh_bf,
                         const float* __restrict__ b_lin, float* __restrict__ out,
                         int* __restrict__ flags) {
    int gid = blockIdx.x * blockDim.x + threadIdx.x;    // 0..196607, each converts 4
    const float4 w = ((const float4*)W_hh)[gid];
    ushort4 o;
    o.x = f2bf(w.x); o.y = f2bf(w.y); o.z = f2bf(w.z); o.w = f2bf(w.w);
    ((ushort4*)whh_bf)[gid] = o;
    if (gid < B_ * OUT_) {
        int oo = gid % OUT_;
        out[gid] = b_lin[oo] + b_lin[OUT_ + oo] + b_lin[2 * OUT_ + oo];
    }
    if (gid < 192 * FLAG_STRIDE) flags[gid] = 0;
}

// Main: 192 blocks = 96 trunk-pairs x 2 column-halves. W_hh slice register-resident
// (R2's monolithic loop shape — do not restructure, it breaks residency).
// Exchange: padded per-block flag lines, 1-thread relaxed spin, parity dbuf.
__global__ __launch_bounds__(256, 1)
void lstm_main(const float* __restrict__ bfeat, const int* __restrict__ trunk_idx,
               const int* __restrict__ trunk_len,
               const unsigned short* __restrict__ whh_bf,
               const float* __restrict__ u, const float* __restrict__ v,
               const float* __restrict__ W_lin,
               unsigned short* __restrict__ hx, int* __restrict__ flags,
               float* __restrict__ out) {
    __shared__ __align__(16) unsigned short hbuf[64][264];   // full h, bf16, +8 pad
    __shared__ __align__(16) float svals[64];

    const int bid = blockIdx.x;
    const int q16 = bid & 15;
    const int cb  = q16 >> 3;                        // column half
    const int pair = (bid >> 4) * 8 + (q16 & 7);     // partner bid^8 -> same XCD
    const int pbid = bid ^ 8;
    const int l = pair >> 5;
    const int t = pair & 31;

    const int tid = threadIdx.x;
    const int w = tid >> 6;
    const int lane = tid & 63;
    const int col = lane & 15;
    const int q = lane >> 4;

    const unsigned short* whh_l = whh_bf + (size_t)l * FH * H_;

    // W_hh slice -> registers (held whole kernel). Wave w owns gate cols
    // j = g*256 + cb*128 + w*32 + n*16 + col.
    short8 Breg[8][8];                   // [g*2+n][ks]
    #pragma unroll
    for (int g = 0; g < 4; ++g)
        #pragma unroll
        for (int n = 0; n < 2; ++n) {
            int j = g * 256 + cb * 128 + w * 32 + n * 16 + col;
            const unsigned short* bp = whh_l + (size_t)j * H_ + q * 8;
            #pragma unroll
            for (int ks = 0; ks < 8; ++ks)
                Breg[g * 2 + n][ks] = *(const short8*)(bp + ks * 32);
        }

    float u_r[4][2], v_r[4][2];
    {
        const float* u_l = u + l * FH;
        const float* v_l = v + l * FH;
        #pragma unroll
        for (int g = 0; g < 4; ++g)
            #pragma unroll
            for (int n = 0; n < 2; ++n) {
                int j = g * 256 + cb * 128 + w * 32 + n * 16 + col;
                u_r[g][n] = u_l[j];
                v_r[g][n] = v_l[j];
            }
    }

    f32x4 c_r[4][2];
    ushort4 hb16[4][2];                  // new h (bf16) staged until S2
    #pragma unroll
    for (int mt = 0; mt < 4; ++mt)
        #pragma unroll
        for (int n = 0; n < 2; ++n)
            #pragma unroll
            for (int rg = 0; rg < 4; ++rg) c_r[mt][n][rg] = 0.0f;

    int len = trunk_len[l * NT + t];
    if (len < 1) len = 1;
    const int* tix = trunk_idx + (l * NT + t) * TL;

    unsigned short* hx_own = hx + (size_t)bid * 16384;        // 2 parity buffers x 8192
    const unsigned short* hx_par = hx + (size_t)pbid * 16384;
    const int prow = tid >> 2;           // 64 B per thread for publish/pull
    const int pcol = (tid & 3) * 32;

    for (int p = 0; p < len; ++p) {
        if (tid < 64) svals[tid] = bfeat[tid * N_ + tix[p]];

        if (p > 0) {
            if (tid == 0) {
                while (__hip_atomic_load(&flags[pbid * FLAG_STRIDE], __ATOMIC_RELAXED,
                                         __HIP_MEMORY_SCOPE_AGENT) < p)
                    __builtin_amdgcn_s_sleep(1);
            }
            __syncthreads();   // flag observed by all
            __builtin_amdgcn_fence(__ATOMIC_ACQUIRE, "agent");
            const ull* src = (const ull*)(hx_par + (size_t)((p & 1) * 8192) + prow * 128 + pcol);
            ull* dst = (ull*)&hbuf[prow][(1 - cb) * 128 + pcol];
            #pragma unroll
            for (int i = 0; i < 8; ++i)
                dst[i] = __hip_atomic_load(&src[i], __ATOMIC_RELAXED, __HIP_MEMORY_SCOPE_AGENT);
        }
        __syncthreads();   // B1: svals + partner half + prev hbuf writes visible

        f32x4 sv[4];
        #pragma unroll
        for (int mt = 0; mt < 4; ++mt) sv[mt] = *(const f32x4*)&svals[mt * 16 + q * 4];

        #pragma unroll
        for (int mt = 0; mt < 4; ++mt) {
            f32x4 acc[4][2];
            #pragma unroll
            for (int g = 0; g < 4; ++g)
                #pragma unroll
                for (int n = 0; n < 2; ++n)
                    #pragma unroll
                    for (int rg = 0; rg < 4; ++rg)
                        acc[g][n][rg] = sv[mt][rg] * u_r[g][n] + v_r[g][n];

            if (p > 0) {
                short8 a_f[8];
                #pragma unroll
                for (int ks = 0; ks < 8; ++ks)
                    a_f[ks] = *(const short8*)&hbuf[mt * 16 + col][ks * 32 + q * 8];
                #pragma unroll
                for (int g = 0; g < 4; ++g)
                    #pragma unroll
                    for (int n = 0; n < 2; ++n)
                        #pragma unroll
                        for (int ks = 0; ks < 8; ++ks)
                            acc[g][n] = __builtin_amdgcn_mfma_f32_16x16x32_bf16(
                                a_f[ks], Breg[g * 2 + n][ks], acc[g][n], 0, 0, 0);
            }

            #pragma unroll
            for (int n = 0; n < 2; ++n) {
                ushort4 hb;
                #pragma unroll
                for (int rg = 0; rg < 4; ++rg) {
                    float si = sigmoidf_(acc[0][n][rg]);
                    float sf = sigmoidf_(acc[1][n][rg]);
                    float tg = tanhf_(acc[2][n][rg]);
                    float so = sigmoidf_(acc[3][n][rg]);
                    float cn = sf * c_r[mt][n][rg] + si * tg;
                    c_r[mt][n][rg] = cn;
                    ((unsigned short*)&hb)[rg] = f2bf(so * tanhf_(cn));
                }
                hb16[mt][n] = hb;
            }
        }

        __syncthreads();   // S2: all waves done reading old h

        #pragma unroll
        for (int mt = 0; mt < 4; ++mt)
            #pragma unroll
            for (int n = 0; n < 2; ++n)
                #pragma unroll
                for (int rg = 0; rg < 4; ++rg)
                    hbuf[mt * 16 + q * 4 + rg][cb * 128 + w * 32 + n * 16 + col] =
                        ((unsigned short*)&hb16[mt][n])[rg];
        __syncthreads();   // S3: own half complete in LDS

        if (p + 1 < len) {
            ull* dst = (ull*)(hx_own + (size_t)(((p + 1) & 1) * 8192) + prow * 128 + pcol);
            const ull* src = (const ull*)&hbuf[prow][cb * 128 + pcol];
            #pragma unroll
            for (int i = 0; i < 8; ++i)
                __hip_atomic_store(&dst[i], src[i], __ATOMIC_RELAXED, __HIP_MEMORY_SCOPE_AGENT);
            __builtin_amdgcn_fence(__ATOMIC_RELEASE, "agent");
            __syncthreads();   // S4: publish stores drained by all waves
            if (tid == 0)
                __hip_atomic_store(&flags[bid * FLAG_STRIDE], p + 1,
                                   __ATOMIC_RELEASE, __HIP_MEMORY_SCOPE_AGENT);
        }
    }

    __syncthreads();
    const float* wl = W_lin + l * H_ * OUT_;
    for (int task = tid; task < B_ * OUT_; task += 256) {
        int m = task / OUT_, o = task % OUT_;
        float s = 0.f;
        for (int k = 0; k < 128; ++k)
            s += bf2f(hbuf[m][cb * 128 + k]) * wl[(cb * 128 + k) * OUT_ + o];
        atomicAdd(&out[m * OUT_ + o], s);
    }
}

extern "C" void kernel_launch(void* const* d_in, const int* in_sizes, int n_in,
                              void* d_out, int out_size, void* d_ws, size_t ws_size,
                              hipStream_t stream) {
    const float* bfeat = (const float*)d_in[0];
    const int*   tidx  = (const int*)d_in[1];
    const int*   tlen  = (const int*)d_in[2];
    const float* W_enc = (const float*)d_in[3];
    const float* b_enc = (const float*)d_in[4];
    const float* W_ih  = (const float*)d_in[5];
    const float* W_hh  = (const float*)d_in[6];
    const float* b_ih  = (const float*)d_in[7];
    const float* b_hh  = (const float*)d_in[8];
    const float* W_lin = (const float*)d_in[9];
    const float* b_lin = (const float*)d_in[10];
    float* out = (float*)d_out;

    unsigned short* whh_bf = (unsigned short*)d_ws;                       // 1,572,864 B
    float* u = (float*)((char*)d_ws + 1572864);                           // 12,288 B
    float* v = (float*)((char*)d_ws + 1572864 + 12288);                   // 12,288 B
    unsigned short* hx = (unsigned short*)((char*)d_ws + 1597440);        // 6,291,456 B
    int* flags = (int*)((char*)d_ws + 1597440 + 6291456);                 // 49,152 B padded

    prep_uv<<<LV * FH, 64, 0, stream>>>(W_enc, b_enc, W_ih, b_ih, b_hh, u, v);
    prep_whh<<<768, 256, 0, stream>>>(W_hh, whh_bf, b_lin, out, flags);
    lstm_main<<<192, 256, 0, stream>>>(bfeat, tidx, tlen, whh_bf, u, v, W_lin, hx, flags, out);
}

// Round 5
// 557.855 us; speedup vs baseline: 1.3717x; 1.3224x over previous
//
#include <hip/hip_runtime.h>
#include <hip/hip_bf16.h>
#include <stdint.h>

#define B_   64
#define N_   128
#define H_   256
#define FH   1024   // 4*H
#define NT   32     // trunks
#define TL   32     // trunk len
#define LV   3
#define OUT_ 10
#define FLAG_STRIDE 64   // ints: one flag per 256 B line

typedef __attribute__((ext_vector_type(8))) short short8;
typedef __attribute__((ext_vector_type(4))) float f32x4;
typedef unsigned long long ull;

__device__ inline float sigmoidf_(float x) { return 1.0f / (1.0f + __expf(-x)); }
__device__ inline float tanhf_(float x) { float t = __expf(2.0f * x); return 1.0f - 2.0f / (t + 1.0f); }
__device__ inline unsigned short f2bf(float x) {
    union { float f; unsigned u; } v; v.f = x;
    unsigned r = (v.u + 0x7FFFu + ((v.u >> 16) & 1u)) >> 16;
    return (unsigned short)r;
}
__device__ inline float bf2f(unsigned short b) {
    union { unsigned u; float f; } v; v.u = ((unsigned)b) << 16; return v.f;
}

// prep 1: u[l][j] = W_ih[l][j,:] . W_enc ;  v[l][j] = W_ih[l][j,:] . b_enc + b_ih + b_hh
__global__ void prep_uv(const float* __restrict__ W_enc, const float* __restrict__ b_enc,
                        const float* __restrict__ W_ih, const float* __restrict__ b_ih,
                        const float* __restrict__ b_hh,
                        float* __restrict__ u, float* __restrict__ v) {
    int j = blockIdx.x;            // 0..3071
    int lane = threadIdx.x;        // 0..63
    const float4 w  = ((const float4*)(W_ih + (size_t)j * H_))[lane];
    const float4 we = ((const float4*)W_enc)[lane];
    const float4 be = ((const float4*)b_enc)[lane];
    float du = w.x * we.x + w.y * we.y + w.z * we.z + w.w * we.w;
    float dv = w.x * be.x + w.y * be.y + w.z * be.z + w.w * be.w;
    for (int m = 32; m >= 1; m >>= 1) { du += __shfl_xor(du, m); dv += __shfl_xor(dv, m); }
    if (lane == 0) { u[j] = du; v[j] = dv + b_ih[j] + b_hh[j]; }
}

// prep 2: W_hh -> bf16 ; init out with sum_l b_lin ; zero the (padded) exchange flags
__global__ void prep_whh(const float* __restrict__ W_hh, unsigned short* __restrict__ whh_bf,
                         const float* __restrict__ b_lin, float* __restrict__ out,
                         int* __restrict__ flags) {
    int gid = blockIdx.x * blockDim.x + threadIdx.x;    // 0..196607, each converts 4
    const float4 w = ((const float4*)W_hh)[gid];
    ushort4 o;
    o.x = f2bf(w.x); o.y = f2bf(w.y); o.z = f2bf(w.z); o.w = f2bf(w.w);
    ((ushort4*)whh_bf)[gid] = o;
    if (gid < B_ * OUT_) {
        int oo = gid % OUT_;
        out[gid] = b_lin[oo] + b_lin[OUT_ + oo] + b_lin[2 * OUT_ + oo];
    }
    if (gid < 192 * FLAG_STRIDE) flags[gid] = 0;
}

// Main: 192 blocks = 96 trunk-pairs x 2 column-halves. W_hh slice register-resident
// (monolithic loop shape — restructuring breaks residency, see R3).
// Exchange: ALL cross-block accesses are RELAXED agent-scope atomics (sc1,
// L2-bypassing, L3-coherent). NO fences, NO release stores — those emit
// buffer_inv / buffer_wbl2 (full per-XCD L2 maintenance) every step, the R2-R4
// suspected serializer. Ordering: __syncthreads drains vmcnt(0) before the
// flag store issues; readers' bypassing loads then see payload at L3.
__global__ __launch_bounds__(256, 1)
void lstm_main(const float* __restrict__ bfeat, const int* __restrict__ trunk_idx,
               const int* __restrict__ trunk_len,
               const unsigned short* __restrict__ whh_bf,
               const float* __restrict__ u, const float* __restrict__ v,
               const float* __restrict__ W_lin,
               unsigned short* __restrict__ hx, int* __restrict__ flags,
               float* __restrict__ out) {
    __shared__ __align__(16) unsigned short hbuf[64][264];   // full h, bf16, +8 pad
    __shared__ __align__(16) float svals[64];

    const int bid = blockIdx.x;
    const int q16 = bid & 15;
    const int cb  = q16 >> 3;                        // column half
    const int pair = (bid >> 4) * 8 + (q16 & 7);     // partner bid^8 -> same XCD
    const int pbid = bid ^ 8;
    const int l = pair >> 5;
    const int t = pair & 31;

    const int tid = threadIdx.x;
    const int w = tid >> 6;
    const int lane = tid & 63;
    const int col = lane & 15;
    const int q = lane >> 4;

    const unsigned short* whh_l = whh_bf + (size_t)l * FH * H_;

    // W_hh slice -> registers (held whole kernel). Wave w owns gate cols
    // j = g*256 + cb*128 + w*32 + n*16 + col.
    short8 Breg[8][8];                   // [g*2+n][ks]
    #pragma unroll
    for (int g = 0; g < 4; ++g)
        #pragma unroll
        for (int n = 0; n < 2; ++n) {
            int j = g * 256 + cb * 128 + w * 32 + n * 16 + col;
            const unsigned short* bp = whh_l + (size_t)j * H_ + q * 8;
            #pragma unroll
            for (int ks = 0; ks < 8; ++ks)
                Breg[g * 2 + n][ks] = *(const short8*)(bp + ks * 32);
        }

    float u_r[4][2], v_r[4][2];
    {
        const float* u_l = u + l * FH;
        const float* v_l = v + l * FH;
        #pragma unroll
        for (int g = 0; g < 4; ++g)
            #pragma unroll
            for (int n = 0; n < 2; ++n) {
                int j = g * 256 + cb * 128 + w * 32 + n * 16 + col;
                u_r[g][n] = u_l[j];
                v_r[g][n] = v_l[j];
            }
    }

    f32x4 c_r[4][2];
    ushort4 hb16[4][2];                  // new h (bf16) staged until S2
    #pragma unroll
    for (int mt = 0; mt < 4; ++mt)
        #pragma unroll
        for (int n = 0; n < 2; ++n)
            #pragma unroll
            for (int rg = 0; rg < 4; ++rg) c_r[mt][n][rg] = 0.0f;

    int len = trunk_len[l * NT + t];
    if (len < 1) len = 1;
    const int* tix = trunk_idx + (l * NT + t) * TL;

    unsigned short* hx_own = hx + (size_t)bid * 16384;        // 2 parity buffers x 8192
    const unsigned short* hx_par = hx + (size_t)pbid * 16384;
    const int prow = tid >> 2;           // 64 B per thread for publish/pull
    const int pcol = (tid & 3) * 32;

    for (int p = 0; p < len; ++p) {
        if (tid < 64) svals[tid] = bfeat[tid * N_ + tix[p]];

        if (p > 0) {
            if (tid == 0) {
                while (__hip_atomic_load(&flags[pbid * FLAG_STRIDE], __ATOMIC_RELAXED,
                                         __HIP_MEMORY_SCOPE_AGENT) < p)
                    __builtin_amdgcn_s_sleep(1);
            }
            __syncthreads();   // flag observed by all
            const ull* src = (const ull*)(hx_par + (size_t)((p & 1) * 8192) + prow * 128 + pcol);
            ull* dst = (ull*)&hbuf[prow][(1 - cb) * 128 + pcol];
            #pragma unroll
            for (int i = 0; i < 8; ++i)
                dst[i] = __hip_atomic_load(&src[i], __ATOMIC_RELAXED, __HIP_MEMORY_SCOPE_AGENT);
        }
        __syncthreads();   // B1: svals + partner half + prev hbuf writes visible

        f32x4 sv[4];
        #pragma unroll
        for (int mt = 0; mt < 4; ++mt) sv[mt] = *(const f32x4*)&svals[mt * 16 + q * 4];

        #pragma unroll
        for (int mt = 0; mt < 4; ++mt) {
            f32x4 acc[4][2];
            #pragma unroll
            for (int g = 0; g < 4; ++g)
                #pragma unroll
                for (int n = 0; n < 2; ++n)
                    #pragma unroll
                    for (int rg = 0; rg < 4; ++rg)
                        acc[g][n][rg] = sv[mt][rg] * u_r[g][n] + v_r[g][n];

            if (p > 0) {
                short8 a_f[8];
                #pragma unroll
                for (int ks = 0; ks < 8; ++ks)
                    a_f[ks] = *(const short8*)&hbuf[mt * 16 + col][ks * 32 + q * 8];
                #pragma unroll
                for (int g = 0; g < 4; ++g)
                    #pragma unroll
                    for (int n = 0; n < 2; ++n)
                        #pragma unroll
                        for (int ks = 0; ks < 8; ++ks)
                            acc[g][n] = __builtin_amdgcn_mfma_f32_16x16x32_bf16(
                                a_f[ks], Breg[g * 2 + n][ks], acc[g][n], 0, 0, 0);
            }

            #pragma unroll
            for (int n = 0; n < 2; ++n) {
                ushort4 hb;
                #pragma unroll
                for (int rg = 0; rg < 4; ++rg) {
                    float si = sigmoidf_(acc[0][n][rg]);
                    float sf = sigmoidf_(acc[1][n][rg]);
                    float tg = tanhf_(acc[2][n][rg]);
                    float so = sigmoidf_(acc[3][n][rg]);
                    float cn = sf * c_r[mt][n][rg] + si * tg;
                    c_r[mt][n][rg] = cn;
                    ((unsigned short*)&hb)[rg] = f2bf(so * tanhf_(cn));
                }
                hb16[mt][n] = hb;
            }
        }

        __syncthreads();   // S2: all waves done reading old h

        #pragma unroll
        for (int mt = 0; mt < 4; ++mt)
            #pragma unroll
            for (int n = 0; n < 2; ++n)
                #pragma unroll
                for (int rg = 0; rg < 4; ++rg)
                    hbuf[mt * 16 + q * 4 + rg][cb * 128 + w * 32 + n * 16 + col] =
                        ((unsigned short*)&hb16[mt][n])[rg];
        __syncthreads();   // S3: own half complete in LDS

        if (p + 1 < len) {
            ull* dst = (ull*)(hx_own + (size_t)(((p + 1) & 1) * 8192) + prow * 128 + pcol);
            const ull* src = (const ull*)&hbuf[prow][cb * 128 + pcol];
            #pragma unroll
            for (int i = 0; i < 8; ++i)
                __hip_atomic_store(&dst[i], src[i], __ATOMIC_RELAXED, __HIP_MEMORY_SCOPE_AGENT);
            __syncthreads();   // S4: publish stores drained (barrier waits vmcnt(0))
            if (tid == 0)
                __hip_atomic_store(&flags[bid * FLAG_STRIDE], p + 1,
                                   __ATOMIC_RELAXED, __HIP_MEMORY_SCOPE_AGENT);
        }
    }

    __syncthreads();
    const float* wl = W_lin + l * H_ * OUT_;
    for (int task = tid; task < B_ * OUT_; task += 256) {
        int m = task / OUT_, o = task % OUT_;
        float s = 0.f;
        for (int k = 0; k < 128; ++k)
            s += bf2f(hbuf[m][cb * 128 + k]) * wl[(cb * 128 + k) * OUT_ + o];
        atomicAdd(&out[m * OUT_ + o], s);
    }
}

extern "C" void kernel_launch(void* const* d_in, const int* in_sizes, int n_in,
                              void* d_out, int out_size, void* d_ws, size_t ws_size,
                              hipStream_t stream) {
    const float* bfeat = (const float*)d_in[0];
    const int*   tidx  = (const int*)d_in[1];
    const int*   tlen  = (const int*)d_in[2];
    const float* W_enc = (const float*)d_in[3];
    const float* b_enc = (const float*)d_in[4];
    const float* W_ih  = (const float*)d_in[5];
    const float* W_hh  = (const float*)d_in[6];
    const float* b_ih  = (const float*)d_in[7];
    const float* b_hh  = (const float*)d_in[8];
    const float* W_lin = (const float*)d_in[9];
    const float* b_lin = (const float*)d_in[10];
    float* out = (float*)d_out;

    unsigned short* whh_bf = (unsigned short*)d_ws;                       // 1,572,864 B
    float* u = (float*)((char*)d_ws + 1572864);                           // 12,288 B
    float* v = (float*)((char*)d_ws + 1572864 + 12288);                   // 12,288 B
    unsigned short* hx = (unsigned short*)((char*)d_ws + 1597440);        // 6,291,456 B
    int* flags = (int*)((char*)d_ws + 1597440 + 6291456);                 // 49,152 B padded

    prep_uv<<<LV * FH, 64, 0, stream>>>(W_enc, b_enc, W_ih, b_ih, b_hh, u, v);
    prep_whh<<<768, 256, 0, stream>>>(W_hh, whh_bf, b_lin, out, flags);
    lstm_main<<<192, 256, 0, stream>>>(bfeat, tidx, tlen, whh_bf, u, v, W_lin, hx, flags, out);
}

// Round 6
// 306.053 us; speedup vs baseline: 2.5002x; 1.8227x over previous
//
#include <hip/hip_runtime.h>
#include <hip/hip_bf16.h>
#include <stdint.h>

#define B_   64
#define N_   128
#define H_   256
#define FH   1024   // 4*H
#define NT   32     // trunks
#define TL   32     // trunk len
#define LV   3
#define OUT_ 10

typedef __attribute__((ext_vector_type(4))) int   int4v;
typedef __attribute__((ext_vector_type(4))) float f32x4;

#define QW (0.0625f / 127.0f)          // weight quant scale
#define QH (1.0f / 127.0f)             // h quant scale
#define QS (QW * QH)                   // combined dequant for i32 acc

__device__ inline float sigmoidf_(float x) { return 1.0f / (1.0f + __expf(-x)); }
__device__ inline float tanhf_(float x) { float t = __expf(2.0f * x); return 1.0f - 2.0f / (t + 1.0f); }

// prep 1: u[l][j] = W_ih[l][j,:] . W_enc ;  v[l][j] = W_ih[l][j,:] . b_enc + b_ih + b_hh
__global__ void prep_uv(const float* __restrict__ W_enc, const float* __restrict__ b_enc,
                        const float* __restrict__ W_ih, const float* __restrict__ b_ih,
                        const float* __restrict__ b_hh,
                        float* __restrict__ u, float* __restrict__ v) {
    int j = blockIdx.x;            // 0..3071
    int lane = threadIdx.x;        // 0..63
    const float4 w  = ((const float4*)(W_ih + (size_t)j * H_))[lane];
    const float4 we = ((const float4*)W_enc)[lane];
    const float4 be = ((const float4*)b_enc)[lane];
    float du = w.x * we.x + w.y * we.y + w.z * we.z + w.w * we.w;
    float dv = w.x * be.x + w.y * be.y + w.z * be.z + w.w * be.w;
    for (int m = 32; m >= 1; m >>= 1) { du += __shfl_xor(du, m); dv += __shfl_xor(dv, m); }
    if (lane == 0) { u[j] = du; v[j] = dv + b_ih[j] + b_hh[j]; }
}

// prep 2: W_hh -> int8 (scale QW) ; init out with sum_l b_lin
__global__ void prep_whh(const float* __restrict__ W_hh, char* __restrict__ whh_i8,
                         const float* __restrict__ b_lin, float* __restrict__ out) {
    int gid = blockIdx.x * blockDim.x + threadIdx.x;    // 0..196607, each converts 4
    const float4 w = ((const float4*)W_hh)[gid];
    char4 o;
    int a0 = __float2int_rn(w.x * (1.0f / QW));
    int a1 = __float2int_rn(w.y * (1.0f / QW));
    int a2 = __float2int_rn(w.z * (1.0f / QW));
    int a3 = __float2int_rn(w.w * (1.0f / QW));
    a0 = a0 > 127 ? 127 : (a0 < -127 ? -127 : a0);
    a1 = a1 > 127 ? 127 : (a1 < -127 ? -127 : a1);
    a2 = a2 > 127 ? 127 : (a2 < -127 ? -127 : a2);
    a3 = a3 > 127 ? 127 : (a3 < -127 ? -127 : a3);
    o.x = (char)a0; o.y = (char)a1; o.z = (char)a2; o.w = (char)a3;
    ((char4*)whh_i8)[gid] = o;
    if (gid < B_ * OUT_) {
        int oo = gid % OUT_;
        out[gid] = b_lin[oo] + b_lin[OUT_ + oo] + b_lin[2 * OUT_ + oo];
    }
}

// Main: 192 independent blocks = 3 levels x 32 trunks x 2 batch-halves.
// 512 threads (8 waves, 2/SIMD). Each block: M=32 rows, ALL 1024 gate cols,
// K=256. Full W_hh (int8) register-resident: 32 KB/wave = 128 VGPRs.
// NO cross-block communication. 2 barriers per step.
__global__ __launch_bounds__(512, 2)
void lstm_main(const float* __restrict__ bfeat, const int* __restrict__ trunk_idx,
               const int* __restrict__ trunk_len,
               const char* __restrict__ whh_i8,
               const float* __restrict__ u, const float* __restrict__ v,
               const float* __restrict__ W_lin, float* __restrict__ out) {
    __shared__ __align__(16) char hbuf[32][272];   // int8 h, 256 + 16 pad
    __shared__ __align__(16) float svals[32];

    const int bid = blockIdx.x;
    const int l = bid >> 6;
    const int rem = bid & 63;
    const int t = rem >> 1;
    const int b0 = (rem & 1) * 32;

    const int tid = threadIdx.x;
    const int w = tid >> 6;              // wave 0..7 -> h-cols [w*32, w*32+32)
    const int lane = tid & 63;
    const int col = lane & 15;
    const int q = lane >> 4;

    const char* whh_l = whh_i8 + (size_t)l * FH * H_;

    // W_hh slice -> registers. Wave w owns gate cols j = g*256 + w*32 + n*16 + col.
    // Breg[g*2+n][k] = 16 int8 of W[j][k*64 + q*16 .. +16)  (B-frag for 16x16x64 i8)
    int4v Breg[8][4];                    // 128 VGPRs
    #pragma unroll
    for (int g = 0; g < 4; ++g)
        #pragma unroll
        for (int n = 0; n < 2; ++n) {
            int j = g * 256 + w * 32 + n * 16 + col;
            const char* bp = whh_l + (size_t)j * H_ + q * 16;
            #pragma unroll
            for (int k = 0; k < 4; ++k)
                Breg[g * 2 + n][k] = *(const int4v*)(bp + k * 64);
        }

    float u_r[4][2], v_r[4][2];
    {
        const float* u_l = u + l * FH;
        const float* v_l = v + l * FH;
        #pragma unroll
        for (int g = 0; g < 4; ++g)
            #pragma unroll
            for (int n = 0; n < 2; ++n) {
                int j = g * 256 + w * 32 + n * 16 + col;
                u_r[g][n] = u_l[j];
                v_r[g][n] = v_l[j];
            }
    }

    float c_r[2][2][4];                  // [mt][n][rg]
    char  h8[2][2][4];                   // staged new h (int8)
    #pragma unroll
    for (int mt = 0; mt < 2; ++mt)
        #pragma unroll
        for (int n = 0; n < 2; ++n)
            #pragma unroll
            for (int rg = 0; rg < 4; ++rg) c_r[mt][n][rg] = 0.0f;

    int len = trunk_len[l * NT + t];
    if (len < 1) len = 1;
    const int* tix = trunk_idx + (l * NT + t) * TL;

    for (int p = 0; p < len; ++p) {
        if (tid < 32) svals[tid] = bfeat[(b0 + tid) * N_ + tix[p]];
        __syncthreads();   // B1: svals ready; prev-step h writes visible

        #pragma unroll
        for (int mt = 0; mt < 2; ++mt) {
            f32x4 sv = *(const f32x4*)&svals[mt * 16 + q * 4];

            int4v acc[4][2];
            #pragma unroll
            for (int g = 0; g < 4; ++g)
                #pragma unroll
                for (int n = 0; n < 2; ++n)
                    #pragma unroll
                    for (int rg = 0; rg < 4; ++rg) acc[g][n][rg] = 0;

            if (p > 0) {
                int4v a_f[4];
                #pragma unroll
                for (int k = 0; k < 4; ++k)
                    a_f[k] = *(const int4v*)&hbuf[mt * 16 + col][k * 64 + q * 16];
                #pragma unroll
                for (int g = 0; g < 4; ++g)
                    #pragma unroll
                    for (int n = 0; n < 2; ++n)
                        #pragma unroll
                        for (int k = 0; k < 4; ++k)
                            acc[g][n] = __builtin_amdgcn_mfma_i32_16x16x64_i8(
                                a_f[k], Breg[g * 2 + n][k], acc[g][n], 0, 0, 0);
            }

            #pragma unroll
            for (int n = 0; n < 2; ++n)
                #pragma unroll
                for (int rg = 0; rg < 4; ++rg) {
                    float iv = QS * (float)acc[0][n][rg] + sv[rg] * u_r[0][n] + v_r[0][n];
                    float fv = QS * (float)acc[1][n][rg] + sv[rg] * u_r[1][n] + v_r[1][n];
                    float gv = QS * (float)acc[2][n][rg] + sv[rg] * u_r[2][n] + v_r[2][n];
                    float ov = QS * (float)acc[3][n][rg] + sv[rg] * u_r[3][n] + v_r[3][n];
                    float si = sigmoidf_(iv);
                    float sf = sigmoidf_(fv);
                    float tg = tanhf_(gv);
                    float so = sigmoidf_(ov);
                    float cn = sf * c_r[mt][n][rg] + si * tg;
                    c_r[mt][n][rg] = cn;
                    float hn = so * tanhf_(cn);
                    h8[mt][n][rg] = (char)__float2int_rn(hn * 127.0f);
                }
        }

        __syncthreads();   // B2: all waves done reading old h

        #pragma unroll
        for (int mt = 0; mt < 2; ++mt)
            #pragma unroll
            for (int n = 0; n < 2; ++n)
                #pragma unroll
                for (int rg = 0; rg < 4; ++rg)
                    hbuf[mt * 16 + q * 4 + rg][w * 32 + n * 16 + col] = h8[mt][n][rg];
        // next-iteration B1 makes these writes visible before reads
    }

    __syncthreads();   // final h writes visible for epilogue

    // epilogue: dequant h_last, project to OUT, accumulate
    const float* wl = W_lin + l * H_ * OUT_;
    for (int task = tid; task < 32 * OUT_; task += 512) {
        int m = task / OUT_, o = task % OUT_;
        float s = 0.f;
        for (int k = 0; k < H_; ++k)
            s += (float)hbuf[m][k] * QH * wl[k * OUT_ + o];
        atomicAdd(&out[(b0 + m) * OUT_ + o], s);
    }
}

extern "C" void kernel_launch(void* const* d_in, const int* in_sizes, int n_in,
                              void* d_out, int out_size, void* d_ws, size_t ws_size,
                              hipStream_t stream) {
    const float* bfeat = (const float*)d_in[0];
    const int*   tidx  = (const int*)d_in[1];
    const int*   tlen  = (const int*)d_in[2];
    const float* W_enc = (const float*)d_in[3];
    const float* b_enc = (const float*)d_in[4];
    const float* W_ih  = (const float*)d_in[5];
    const float* W_hh  = (const float*)d_in[6];
    const float* b_ih  = (const float*)d_in[7];
    const float* b_hh  = (const float*)d_in[8];
    const float* W_lin = (const float*)d_in[9];
    const float* b_lin = (const float*)d_in[10];
    float* out = (float*)d_out;

    char* whh_i8 = (char*)d_ws;                                // 786,432 B
    float* u = (float*)((char*)d_ws + 786432);                 // 12,288 B
    float* v = (float*)((char*)d_ws + 786432 + 12288);         // 12,288 B

    prep_uv<<<LV * FH, 64, 0, stream>>>(W_enc, b_enc, W_ih, b_ih, b_hh, u, v);
    prep_whh<<<768, 256, 0, stream>>>(W_hh, whh_i8, b_lin, out);
    lstm_main<<<192, 512, 0, stream>>>(bfeat, tidx, tlen, whh_i8, u, v, W_lin, out);
}

// Round 7
// 199.371 us; speedup vs baseline: 3.8380x; 1.5351x over previous
//
#include <hip/hip_runtime.h>
#include <hip/hip_bf16.h>
#include <stdint.h>

#define B_   64
#define N_   128
#define H_   256
#define FH   1024   // 4*H
#define NT   32     // trunks
#define TL   32     // trunk len
#define LV   3
#define OUT_ 10

typedef __attribute__((ext_vector_type(4))) int   int4v;
typedef __attribute__((ext_vector_type(4))) float f32x4;

#define QW (0.0625f / 127.0f)          // weight quant scale
#define QH (1.0f / 127.0f)             // h quant scale
#define QS (QW * QH)                   // combined dequant for i32 acc
#define L2E 1.442695041f               // log2(e)
#define QSI (-L2E * QS)                // sigmoid-gate dequant (pre-negated+scaled)
#define QSG (2.0f * L2E * QS)          // tanh-gate dequant
#define C2  (2.0f * L2E)               // tanh(c) input scale

__device__ inline float exp2f_(float x) { return __builtin_amdgcn_exp2f(x); }
__device__ inline float rcpf_(float x)  { return __builtin_amdgcn_rcpf(x); }

// prep 1: pre-scaled u,v.  raw: du = W_ih[j,:].W_enc ; dv = W_ih[j,:].b_enc + b_ih + b_hh
// stored: u[j] = s_g*du, v[j] = s_g*dv with s_g = -log2e (gates i,f,o) or +2log2e (gate g)
__global__ void prep_uv(const float* __restrict__ W_enc, const float* __restrict__ b_enc,
                        const float* __restrict__ W_ih, const float* __restrict__ b_ih,
                        const float* __restrict__ b_hh,
                        float* __restrict__ u, float* __restrict__ v) {
    int j = blockIdx.x;            // 0..3071  (l*1024 + jj)
    int lane = threadIdx.x;        // 0..63
    const float4 w  = ((const float4*)(W_ih + (size_t)j * H_))[lane];
    const float4 we = ((const float4*)W_enc)[lane];
    const float4 be = ((const float4*)b_enc)[lane];
    float du = w.x * we.x + w.y * we.y + w.z * we.z + w.w * we.w;
    float dv = w.x * be.x + w.y * be.y + w.z * be.z + w.w * be.w;
    for (int m = 32; m >= 1; m >>= 1) { du += __shfl_xor(du, m); dv += __shfl_xor(dv, m); }
    if (lane == 0) {
        int g = (j & 1023) >> 8;
        float s = (g == 2) ? (2.0f * L2E) : (-L2E);
        u[j] = s * du;
        v[j] = s * (dv + b_ih[j] + b_hh[j]);
    }
}

// prep 2: W_hh -> int8 (scale QW) ; init out with sum_l b_lin
__global__ void prep_whh(const float* __restrict__ W_hh, char* __restrict__ whh_i8,
                         const float* __restrict__ b_lin, float* __restrict__ out) {
    int gid = blockIdx.x * blockDim.x + threadIdx.x;    // 0..196607, each converts 4
    const float4 w = ((const float4*)W_hh)[gid];
    char4 o;
    int a0 = __float2int_rn(w.x * (1.0f / QW));
    int a1 = __float2int_rn(w.y * (1.0f / QW));
    int a2 = __float2int_rn(w.z * (1.0f / QW));
    int a3 = __float2int_rn(w.w * (1.0f / QW));
    a0 = a0 > 127 ? 127 : (a0 < -127 ? -127 : a0);
    a1 = a1 > 127 ? 127 : (a1 < -127 ? -127 : a1);
    a2 = a2 > 127 ? 127 : (a2 < -127 ? -127 : a2);
    a3 = a3 > 127 ? 127 : (a3 < -127 ? -127 : a3);
    o.x = (char)a0; o.y = (char)a1; o.z = (char)a2; o.w = (char)a3;
    ((char4*)whh_i8)[gid] = o;
    if (gid < B_ * OUT_) {
        int oo = gid % OUT_;
        out[gid] = b_lin[oo] + b_lin[OUT_ + oo] + b_lin[2 * OUT_ + oo];
    }
}

// Main: 192 independent blocks = 3 levels x 32 trunks x 2 batch-halves.
// 512 threads (8 waves). M=32 rows, all 1024 gate cols, K=256.
// Full W_hh (int8) register-resident (128 VGPR/wave). No cross-block comm.
// ONE barrier/step (parity-double-buffered hbuf) + svals prefetch dbuf.
__global__ __launch_bounds__(512, 2)
void lstm_main(const float* __restrict__ bfeat, const int* __restrict__ trunk_idx,
               const int* __restrict__ trunk_len,
               const char* __restrict__ whh_i8,
               const float* __restrict__ u, const float* __restrict__ v,
               const float* __restrict__ W_lin, float* __restrict__ out) {
    __shared__ __align__(16) char hbuf[2][32][272];   // int8 h, parity dbuf, 256+16 pad
    __shared__ __align__(16) float sbuf[2][32];       // batch scalars, parity dbuf

    const int bid = blockIdx.x;
    const int l = bid >> 6;
    const int rem = bid & 63;
    const int t = rem >> 1;
    const int b0 = (rem & 1) * 32;

    const int tid = threadIdx.x;
    const int w = tid >> 6;              // wave 0..7 -> h-cols [w*32, w*32+32)
    const int lane = tid & 63;
    const int col = lane & 15;
    const int q = lane >> 4;

    const char* whh_l = whh_i8 + (size_t)l * FH * H_;

    // W_hh slice -> registers. Wave w owns gate cols j = g*256 + w*32 + n*16 + col.
    int4v Breg[8][4];                    // [g*2+n][k] : 128 VGPRs
    #pragma unroll
    for (int g = 0; g < 4; ++g)
        #pragma unroll
        for (int n = 0; n < 2; ++n) {
            int j = g * 256 + w * 32 + n * 16 + col;
            const char* bp = whh_l + (size_t)j * H_ + q * 16;
            #pragma unroll
            for (int k = 0; k < 4; ++k)
                Breg[g * 2 + n][k] = *(const int4v*)(bp + k * 64);
        }

    float u_r[4][2], v_r[4][2];          // pre-scaled by prep_uv
    {
        const float* u_l = u + l * FH;
        const float* v_l = v + l * FH;
        #pragma unroll
        for (int g = 0; g < 4; ++g)
            #pragma unroll
            for (int n = 0; n < 2; ++n) {
                int j = g * 256 + w * 32 + n * 16 + col;
                u_r[g][n] = u_l[j];
                v_r[g][n] = v_l[j];
            }
    }

    float c_r[2][2][4];                  // [mt][n][rg]
    #pragma unroll
    for (int mt = 0; mt < 2; ++mt)
        #pragma unroll
        for (int n = 0; n < 2; ++n)
            #pragma unroll
            for (int rg = 0; rg < 4; ++rg) c_r[mt][n][rg] = 0.0f;

    int len = trunk_len[l * NT + t];
    if (len < 1) len = 1;
    const int* tix = trunk_idx + (l * NT + t) * TL;

    // prologue: svals for step 0
    if (tid < 32) sbuf[0][tid] = bfeat[(b0 + tid) * N_ + tix[0]];
    __syncthreads();

    for (int p = 0; p < len; ++p) {
        const int ri = p & 1, wi = ri ^ 1;

        // prefetch next step's batch scalars into the other parity buffer
        if (p + 1 < len && tid < 32)
            sbuf[wi][tid] = bfeat[(b0 + tid) * N_ + tix[p + 1]];

        #pragma unroll
        for (int mt = 0; mt < 2; ++mt) {
            f32x4 sv = *(const f32x4*)&sbuf[ri][mt * 16 + q * 4];

            int4v acc[4][2];
            #pragma unroll
            for (int g = 0; g < 4; ++g)
                #pragma unroll
                for (int n = 0; n < 2; ++n)
                    #pragma unroll
                    for (int rg = 0; rg < 4; ++rg) acc[g][n][rg] = 0;

            if (p > 0) {
                int4v a_f[4];
                #pragma unroll
                for (int k = 0; k < 4; ++k)
                    a_f[k] = *(const int4v*)&hbuf[ri][mt * 16 + col][k * 64 + q * 16];
                #pragma unroll
                for (int g = 0; g < 4; ++g)
                    #pragma unroll
                    for (int n = 0; n < 2; ++n)
                        #pragma unroll
                        for (int k = 0; k < 4; ++k)
                            acc[g][n] = __builtin_amdgcn_mfma_i32_16x16x64_i8(
                                a_f[k], Breg[g * 2 + n][k], acc[g][n], 0, 0, 0);
            }

            #pragma unroll
            for (int n = 0; n < 2; ++n)
                #pragma unroll
                for (int rg = 0; rg < 4; ++rg) {
                    // pre-scaled gate inputs: sigmoid gates carry -log2e, g-gate +2log2e
                    float xi = fmaf((float)acc[0][n][rg], QSI, fmaf(sv[rg], u_r[0][n], v_r[0][n]));
                    float xf = fmaf((float)acc[1][n][rg], QSI, fmaf(sv[rg], u_r[1][n], v_r[1][n]));
                    float xg = fmaf((float)acc[2][n][rg], QSG, fmaf(sv[rg], u_r[2][n], v_r[2][n]));
                    float xo = fmaf((float)acc[3][n][rg], QSI, fmaf(sv[rg], u_r[3][n], v_r[3][n]));
                    float si = rcpf_(exp2f_(xi) + 1.0f);          // sigmoid
                    float sf = rcpf_(exp2f_(xf) + 1.0f);
                    float so = rcpf_(exp2f_(xo) + 1.0f);
                    float tg = fmaf(-2.0f, rcpf_(exp2f_(xg) + 1.0f), 1.0f);   // tanh
                    float cn = fmaf(sf, c_r[mt][n][rg], si * tg);
                    c_r[mt][n][rg] = cn;
                    float th = fmaf(-2.0f, rcpf_(exp2f_(C2 * cn) + 1.0f), 1.0f);
                    float hn = so * th;
                    hbuf[wi][mt * 16 + q * 4 + rg][w * 32 + n * 16 + col] =
                        (char)__float2int_rn(hn * 127.0f);
                }
        }

        __syncthreads();   // single barrier: new h (wi) complete, sbuf[wi] ready
    }

    // epilogue: h_last lives in hbuf[len & 1]
    const char (*hl)[272] = hbuf[len & 1];
    const float* wl = W_lin + l * H_ * OUT_;
    for (int task = tid; task < 32 * OUT_; task += 512) {
        int m = task / OUT_, o = task % OUT_;
        float s = 0.f;
        for (int k = 0; k < H_; ++k)
            s += (float)hl[m][k] * QH * wl[k * OUT_ + o];
        atomicAdd(&out[(b0 + m) * OUT_ + o], s);
    }
}

extern "C" void kernel_launch(void* const* d_in, const int* in_sizes, int n_in,
                              void* d_out, int out_size, void* d_ws, size_t ws_size,
                              hipStream_t stream) {
    const float* bfeat = (const float*)d_in[0];
    const int*   tidx  = (const int*)d_in[1];
    const int*   tlen  = (const int*)d_in[2];
    const float* W_enc = (const float*)d_in[3];
    const float* b_enc = (const float*)d_in[4];
    const float* W_ih  = (const float*)d_in[5];
    const float* W_hh  = (const float*)d_in[6];
    const float* b_ih  = (const float*)d_in[7];
    const float* b_hh  = (const float*)d_in[8];
    const float* W_lin = (const float*)d_in[9];
    const float* b_lin = (const float*)d_in[10];
    float* out = (float*)d_out;

    char* whh_i8 = (char*)d_ws;                                // 786,432 B
    float* u = (float*)((char*)d_ws + 786432);                 // 12,288 B
    float* v = (float*)((char*)d_ws + 786432 + 12288);         // 12,288 B

    prep_uv<<<LV * FH, 64, 0, stream>>>(W_enc, b_enc, W_ih, b_ih, b_hh, u, v);
    prep_whh<<<768, 256, 0, stream>>>(W_hh, whh_i8, b_lin, out);
    lstm_main<<<192, 512, 0, stream>>>(bfeat, tidx, tlen, whh_i8, u, v, W_lin, out);
}

// Round 8
// 197.337 us; speedup vs baseline: 3.8776x; 1.0103x over previous
//
#include <hip/hip_runtime.h>
#include <hip/hip_bf16.h>
#include <stdint.h>

#define B_   64
#define N_   128
#define H_   256
#define FH   1024   // 4*H
#define NT   32     // trunks
#define TL   32     // trunk len
#define LV   3
#define OUT_ 10

typedef __attribute__((ext_vector_type(4))) int   int4v;
typedef __attribute__((ext_vector_type(4))) float f32x4;

#define QW (0.0625f / 127.0f)          // weight quant scale
#define QH (1.0f / 127.0f)             // h quant scale
#define QS (QW * QH)                   // combined dequant for i32 acc
#define L2E 1.442695041f               // log2(e)
#define QSI (-L2E * QS)                // sigmoid-gate dequant (pre-negated+scaled)
#define QSG (2.0f * L2E * QS)          // tanh-gate dequant
#define C2  (2.0f * L2E)               // tanh(c) input scale

__device__ inline float exp2f_(float x) { return __builtin_amdgcn_exp2f(x); }
__device__ inline float rcpf_(float x)  { return __builtin_amdgcn_rcpf(x); }

// merged prep. blocks 0..767: u/v (4 j per block, one per wave).
// blocks 768..1535: W_hh->int8 + out init.
__global__ void prep_all(const float* __restrict__ W_enc, const float* __restrict__ b_enc,
                         const float* __restrict__ W_ih, const float* __restrict__ b_ih,
                         const float* __restrict__ b_hh, const float* __restrict__ W_hh,
                         const float* __restrict__ b_lin,
                         float* __restrict__ u, float* __restrict__ v,
                         char* __restrict__ whh_i8, float* __restrict__ out) {
    int blk = blockIdx.x;
    int tid = threadIdx.x;
    if (blk < 768) {
        int j = blk * 4 + (tid >> 6);   // 0..3071
        int lane = tid & 63;
        const float4 w  = ((const float4*)(W_ih + (size_t)j * H_))[lane];
        const float4 we = ((const float4*)W_enc)[lane];
        const float4 be = ((const float4*)b_enc)[lane];
        float du = w.x * we.x + w.y * we.y + w.z * we.z + w.w * we.w;
        float dv = w.x * be.x + w.y * be.y + w.z * be.z + w.w * be.w;
        for (int m = 32; m >= 1; m >>= 1) { du += __shfl_xor(du, m); dv += __shfl_xor(dv, m); }
        if (lane == 0) {
            int g = (j & 1023) >> 8;
            float s = (g == 2) ? (2.0f * L2E) : (-L2E);
            u[j] = s * du;
            v[j] = s * (dv + b_ih[j] + b_hh[j]);
        }
    } else {
        int gid = (blk - 768) * 256 + tid;   // 0..196607, each converts 4
        const float4 w = ((const float4*)W_hh)[gid];
        char4 o;
        int a0 = __float2int_rn(w.x * (1.0f / QW));
        int a1 = __float2int_rn(w.y * (1.0f / QW));
        int a2 = __float2int_rn(w.z * (1.0f / QW));
        int a3 = __float2int_rn(w.w * (1.0f / QW));
        a0 = a0 > 127 ? 127 : (a0 < -127 ? -127 : a0);
        a1 = a1 > 127 ? 127 : (a1 < -127 ? -127 : a1);
        a2 = a2 > 127 ? 127 : (a2 < -127 ? -127 : a2);
        a3 = a3 > 127 ? 127 : (a3 < -127 ? -127 : a3);
        o.x = (char)a0; o.y = (char)a1; o.z = (char)a2; o.w = (char)a3;
        ((char4*)whh_i8)[gid] = o;
        if (gid < B_ * OUT_) {
            int oo = gid % OUT_;
            out[gid] = b_lin[oo] + b_lin[OUT_ + oo] + b_lin[2 * OUT_ + oo];
        }
    }
}

// Main: 192 independent blocks = 3 levels x 32 trunks x 2 batch-halves.
// 512 threads (8 waves, PINNED 2 waves/EU -> 256 VGPR budget so Breg is truly
// register-resident). M=32 rows, all 1024 gate cols, K=256. No cross-block comm.
// One barrier/step, parity-dbuf hbuf, svals prefetch, step-0 peeled.
__global__ __launch_bounds__(512) __attribute__((amdgpu_waves_per_eu(2, 2)))
void lstm_main(const float* __restrict__ bfeat, const int* __restrict__ trunk_idx,
               const int* __restrict__ trunk_len,
               const char* __restrict__ whh_i8,
               const float* __restrict__ u, const float* __restrict__ v,
               const float* __restrict__ W_lin, float* __restrict__ out) {
    __shared__ __align__(16) char hbuf[2][32][272];   // int8 h, parity dbuf, 256+16 pad
    __shared__ __align__(16) float sbuf[2][32];       // batch scalars, parity dbuf

    const int bid = blockIdx.x;
    const int l = bid >> 6;
    const int rem = bid & 63;
    const int t = rem >> 1;
    const int b0 = (rem & 1) * 32;

    const int tid = threadIdx.x;
    const int w = tid >> 6;              // wave 0..7 -> h-cols [w*32, w*32+32)
    const int lane = tid & 63;
    const int col = lane & 15;
    const int q = lane >> 4;

    const char* whh_l = whh_i8 + (size_t)l * FH * H_;

    // W_hh slice -> registers (128 VGPR). Wave w owns gate cols
    // j = g*256 + w*32 + n*16 + col.
    int4v Breg[8][4];                    // [g*2+n][k]
    #pragma unroll
    for (int g = 0; g < 4; ++g)
        #pragma unroll
        for (int n = 0; n < 2; ++n) {
            int j = g * 256 + w * 32 + n * 16 + col;
            const char* bp = whh_l + (size_t)j * H_ + q * 16;
            #pragma unroll
            for (int k = 0; k < 4; ++k)
                Breg[g * 2 + n][k] = *(const int4v*)(bp + k * 64);
        }

    float u_r[4][2], v_r[4][2];          // pre-scaled by prep
    {
        const float* u_l = u + l * FH;
        const float* v_l = v + l * FH;
        #pragma unroll
        for (int g = 0; g < 4; ++g)
            #pragma unroll
            for (int n = 0; n < 2; ++n) {
                int j = g * 256 + w * 32 + n * 16 + col;
                u_r[g][n] = u_l[j];
                v_r[g][n] = v_l[j];
            }
    }

    float c_r[2][2][4];                  // [mt][n][rg]

    int len = trunk_len[l * NT + t];
    if (len < 1) len = 1;
    const int* tix = trunk_idx + (l * NT + t) * TL;

    // prologue: svals for step 0 (+ step-1 prefetch happens inside step 0)
    if (tid < 32) sbuf[0][tid] = bfeat[(b0 + tid) * N_ + tix[0]];
    __syncthreads();

    // ---- peeled step 0: no h yet (acc = 0) ----
    {
        if (len > 1 && tid < 32) sbuf[1][tid] = bfeat[(b0 + tid) * N_ + tix[1]];
        #pragma unroll
        for (int mt = 0; mt < 2; ++mt) {
            f32x4 sv = *(const f32x4*)&sbuf[0][mt * 16 + q * 4];
            #pragma unroll
            for (int n = 0; n < 2; ++n)
                #pragma unroll
                for (int rg = 0; rg < 4; ++rg) {
                    float xi = fmaf(sv[rg], u_r[0][n], v_r[0][n]);
                    float xf = fmaf(sv[rg], u_r[1][n], v_r[1][n]);
                    float xg = fmaf(sv[rg], u_r[2][n], v_r[2][n]);
                    float xo = fmaf(sv[rg], u_r[3][n], v_r[3][n]);
                    float si = rcpf_(exp2f_(xi) + 1.0f);
                    float so = rcpf_(exp2f_(xo) + 1.0f);
                    float tg = fmaf(-2.0f, rcpf_(exp2f_(xg) + 1.0f), 1.0f);
                    (void)xf;
                    float cn = si * tg;                       // c0 = 0
                    c_r[mt][n][rg] = cn;
                    float th = fmaf(-2.0f, rcpf_(exp2f_(C2 * cn) + 1.0f), 1.0f);
                    hbuf[1][mt * 16 + q * 4 + rg][w * 32 + n * 16 + col] =
                        (char)__float2int_rn(so * th * 127.0f);
                }
        }
        __syncthreads();
    }

    for (int p = 1; p < len; ++p) {
        const int ri = p & 1, wi = ri ^ 1;

        if (p + 1 < len && tid < 32)
            sbuf[wi][tid] = bfeat[(b0 + tid) * N_ + tix[p + 1]];

        // issue all A-fragment LDS reads up front (both mt tiles)
        int4v a_f[2][4];
        #pragma unroll
        for (int mt = 0; mt < 2; ++mt)
            #pragma unroll
            for (int k = 0; k < 4; ++k)
                a_f[mt][k] = *(const int4v*)&hbuf[ri][mt * 16 + col][k * 64 + q * 16];

        #pragma unroll
        for (int mt = 0; mt < 2; ++mt) {
            f32x4 sv = *(const f32x4*)&sbuf[ri][mt * 16 + q * 4];

            int4v acc[4][2];
            #pragma unroll
            for (int g = 0; g < 4; ++g)
                #pragma unroll
                for (int n = 0; n < 2; ++n)
                    #pragma unroll
                    for (int rg = 0; rg < 4; ++rg) acc[g][n][rg] = 0;

            #pragma unroll
            for (int g = 0; g < 4; ++g)
                #pragma unroll
                for (int n = 0; n < 2; ++n)
                    #pragma unroll
                    for (int k = 0; k < 4; ++k)
                        acc[g][n] = __builtin_amdgcn_mfma_i32_16x16x64_i8(
                            a_f[mt][k], Breg[g * 2 + n][k], acc[g][n], 0, 0, 0);

            #pragma unroll
            for (int n = 0; n < 2; ++n)
                #pragma unroll
                for (int rg = 0; rg < 4; ++rg) {
                    float xi = fmaf((float)acc[0][n][rg], QSI, fmaf(sv[rg], u_r[0][n], v_r[0][n]));
                    float xf = fmaf((float)acc[1][n][rg], QSI, fmaf(sv[rg], u_r[1][n], v_r[1][n]));
                    float xg = fmaf((float)acc[2][n][rg], QSG, fmaf(sv[rg], u_r[2][n], v_r[2][n]));
                    float xo = fmaf((float)acc[3][n][rg], QSI, fmaf(sv[rg], u_r[3][n], v_r[3][n]));
                    float si = rcpf_(exp2f_(xi) + 1.0f);          // sigmoid
                    float sf = rcpf_(exp2f_(xf) + 1.0f);
                    float so = rcpf_(exp2f_(xo) + 1.0f);
                    float tg = fmaf(-2.0f, rcpf_(exp2f_(xg) + 1.0f), 1.0f);   // tanh
                    float cn = fmaf(sf, c_r[mt][n][rg], si * tg);
                    c_r[mt][n][rg] = cn;
                    float th = fmaf(-2.0f, rcpf_(exp2f_(C2 * cn) + 1.0f), 1.0f);
                    hbuf[wi][mt * 16 + q * 4 + rg][w * 32 + n * 16 + col] =
                        (char)__float2int_rn(so * th * 127.0f);
                }
        }

        __syncthreads();   // single barrier: new h (wi) + next sbuf ready
    }

    // epilogue: h_last lives in hbuf[len & 1]
    const char (*hl)[272] = hbuf[len & 1];
    const float* wl = W_lin + l * H_ * OUT_;
    for (int task = tid; task < 32 * OUT_; task += 512) {
        int m = task / OUT_, o = task % OUT_;
        float s = 0.f;
        for (int k = 0; k < H_; ++k)
            s += (float)hl[m][k] * QH * wl[k * OUT_ + o];
        atomicAdd(&out[(b0 + m) * OUT_ + o], s);
    }
}

extern "C" void kernel_launch(void* const* d_in, const int* in_sizes, int n_in,
                              void* d_out, int out_size, void* d_ws, size_t ws_size,
                              hipStream_t stream) {
    const float* bfeat = (const float*)d_in[0];
    const int*   tidx  = (const int*)d_in[1];
    const int*   tlen  = (const int*)d_in[2];
    const float* W_enc = (const float*)d_in[3];
    const float* b_enc = (const float*)d_in[4];
    const float* W_ih  = (const float*)d_in[5];
    const float* W_hh  = (const float*)d_in[6];
    const float* b_ih  = (const float*)d_in[7];
    const float* b_hh  = (const float*)d_in[8];
    const float* W_lin = (const float*)d_in[9];
    const float* b_lin = (const float*)d_in[10];
    float* out = (float*)d_out;

    char* whh_i8 = (char*)d_ws;                                // 786,432 B
    float* u = (float*)((char*)d_ws + 786432);                 // 12,288 B
    float* v = (float*)((char*)d_ws + 786432 + 12288);         // 12,288 B

    prep_all<<<1536, 256, 0, stream>>>(W_enc, b_enc, W_ih, b_ih, b_hh, W_hh, b_lin,
                                       u, v, whh_i8, out);
    lstm_main<<<192, 512, 0, stream>>>(bfeat, tidx, tlen, whh_i8, u, v, W_lin, out);
}